// Round 7
// baseline (372.819 us; speedup 1.0000x reference)
//
#include <hip/hip_runtime.h>
#include <hip/hip_bf16.h>
#include <stdint.h>
#include <cstddef>

// Problem constants
#define BB  2
#define CC  512
#define TT  32
#define HWP 196   // H*W = 14*14
#define NH  8
#define KWIN 9
#define CID 64    // C / N
#define PPAD 4    // (K-1)/2
#define TP  40    // T + 2P
#define MTOT 12544  // BB*TT*HWP
#define NTOT 1536   // 3*CC (Q|K|V output channels)
#define VSLOT 224   // padded per-frame key slots (7*32)
#define LOG2E 1.44269504f

typedef unsigned short u16;
typedef unsigned int   u32;
typedef __attribute__((ext_vector_type(8))) short short8;
typedef __attribute__((ext_vector_type(4))) float floatx4;

__device__ __forceinline__ u16 f2bf(float f) {
    u32 u = __float_as_uint(f);
    u32 r = (u + 0x7fffu + ((u >> 16) & 1u)) >> 16;
    return (u16)r;
}
__device__ __forceinline__ u32 pack2bf(float a, float b) {
    return (u32)f2bf(a) | ((u32)f2bf(b) << 16);
}
// Truncating pack: [hi16(b) : hi16(a)] in one v_perm_b32.
__device__ __forceinline__ u32 packtrunc(float a, float b) {
    return __builtin_amdgcn_perm(__float_as_uint(b), __float_as_uint(a), 0x07060302u);
}

// ---------------------------------------------------------------------------
// Prep 1: W concat + fp32->bf16.  Wbf[oc][c], oc = kind*512 + n*64 + ci.
// ---------------------------------------------------------------------------
__global__ __launch_bounds__(256) void convert_w(
    const float* __restrict__ Wq, const float* __restrict__ Wk,
    const float* __restrict__ Wv, u16* __restrict__ Wbf)
{
    int id = blockIdx.x * 256 + threadIdx.x;      // one u32 (2 elems) each
    if (id >= NTOT * CC / 2) return;
    int c2 = id & 255;
    int oc = id >> 8;
    int kind = oc >> 9;
    int idx = oc & 511;
    const float* src = (kind == 0 ? Wq : (kind == 1 ? Wk : Wv)) + (size_t)idx * CC + c2 * 2;
    ((u32*)Wbf)[id] = pack2bf(src[0], src[1]);
}

// ---------------------------------------------------------------------------
// Prep 2: transpose x[b][c][t][p] fp32 -> xt[(b*T+t)*HW+p][c] bf16.
// xt lives in d_out (dead until attn overwrites with z).
// ---------------------------------------------------------------------------
__global__ __launch_bounds__(256) void transpose_x(
    const float* __restrict__ x, u16* __restrict__ xt)
{
    __shared__ float T[64 * 197];
    int bx = blockIdx.x;
    int ct = bx & 7; bx >>= 3;
    int t = bx & 31;
    int b = bx >> 5;
    int tid = threadIdx.x;
    const float* src = x + ((size_t)(b * CC + ct * 64) * TT + t) * HWP;
    for (int i = tid; i < 64 * HWP; i += 256) {
        int c = i / HWP;
        int p = i - c * HWP;
        T[c * 197 + p] = src[(size_t)c * (TT * HWP) + p];
    }
    __syncthreads();
    u16* dst = xt + (size_t)((b * TT + t) * HWP) * CC + ct * 64;
    for (int i = tid; i < HWP * 64; i += 256) {
        int p = i >> 6;
        int c = i & 63;
        dst[(size_t)p * CC + c] = f2bf(T[c * 197 + p]);
    }
}

// ---------------------------------------------------------------------------
// Prep 3: fill pad frames (tp in {0..3, 36..39}): K rows and Vtp rows = bias.
// ---------------------------------------------------------------------------
__global__ __launch_bounds__(256) void pad_fill(
    const float* __restrict__ bk, const float* __restrict__ bv,
    u16* __restrict__ Kout, u16* __restrict__ Vtp)
{
    int id = blockIdx.x * 256 + threadIdx.x;
    const int kper = 2 * NH * 8 * HWP * 32;        // 802816 u32 (K)
    const int vper = 2 * NH * 8 * 64 * (VSLOT/2);  // 917504 u32 (Vtp)
    if (id >= kper + vper) return;
    if (id < kper) {
        int i = id;
        int ci2 = i & 31; i >>= 5;
        int p = i % HWP;  i /= HWP;
        int fr = i & 7;   i >>= 3;
        int head = i & 7;
        int b = i >> 3;
        int tp = fr < 4 ? fr : fr + 32;
        const float* bias = bk + head * CID + ci2 * 2;
        size_t addr = (((size_t)(b * NH + head) * TP + tp) * HWP + p) * 32 + ci2;
        ((u32*)Kout)[addr] = pack2bf(bias[0], bias[1]);
    } else {
        int i = id - kper;
        int s2 = i % (VSLOT/2); i /= (VSLOT/2);
        int ci = i & 63; i >>= 6;
        int fr = i & 7;  i >>= 3;
        int head = i & 7;
        int b = i >> 3;
        int tp = fr < 4 ? fr : fr + 32;
        float bias = bv[head * CID + ci];
        size_t addr = (((size_t)(b * NH + head) * TP + tp) * 64 + ci) * (VSLOT/2) + s2;
        ((u32*)Vtp)[addr] = pack2bf(bias, bias);   // whole row = bias[ci]
    }
}

// ---------------------------------------------------------------------------
// MFMA projection GEMM: Out^T[m=(b,t,p), n=oc] = xt[m,c] . Wbf[n,c] + bias[n].
// Q scaled by log2(e) (exp2 softmax trick). K stored [tp][p][ci]; V stored
// [t][p][ci] over the 32 REAL frames only (coalesced 32B runs); the slot
// permutation is deferred to v_reformat.
// ---------------------------------------------------------------------------
__global__ __launch_bounds__(256) void proj_gemm(
    const u16* __restrict__ xt, const u16* __restrict__ Wbf,
    const float* __restrict__ bq, const float* __restrict__ bk,
    const float* __restrict__ bv,
    u16* __restrict__ Qout, u16* __restrict__ Kout, u16* __restrict__ Vplain)
{
    int bx = blockIdx.x;
    int nb = bx % 6;
    int mt = bx / 6;
    int tid = threadIdx.x;
    int wave = tid >> 6, lane = tid & 63, quad = lane >> 4, l15 = lane & 15;
    int mbase = mt * 64;
    int nbase = nb * 256 + wave * 64;

    floatx4 acc[4][4];
    #pragma unroll
    for (int ms = 0; ms < 4; ms++)
        #pragma unroll
        for (int ns = 0; ns < 4; ns++)
            acc[ms][ns] = (floatx4){0.f, 0.f, 0.f, 0.f};

    const u16* ap[4];
    const u16* bp[4];
    #pragma unroll
    for (int ms = 0; ms < 4; ms++)
        ap[ms] = xt + (size_t)(mbase + ms * 16 + l15) * CC + quad * 8;
    #pragma unroll
    for (int ns = 0; ns < 4; ns++)
        bp[ns] = Wbf + (size_t)(nbase + ns * 16 + l15) * CC + quad * 8;

    #pragma unroll 2
    for (int kc = 0; kc < 16; kc++) {
        short8 af[4], bf[4];
        #pragma unroll
        for (int ms = 0; ms < 4; ms++) af[ms] = *(const short8*)(ap[ms] + kc * 32);
        #pragma unroll
        for (int ns = 0; ns < 4; ns++) bf[ns] = *(const short8*)(bp[ns] + kc * 32);
        #pragma unroll
        for (int ms = 0; ms < 4; ms++)
            #pragma unroll
            for (int ns = 0; ns < 4; ns++)
                acc[ms][ns] = __builtin_amdgcn_mfma_f32_16x16x32_bf16(
                    af[ms], bf[ns], acc[ms][ns], 0, 0, 0);
    }

    float biasv[4];
    #pragma unroll
    for (int ns = 0; ns < 4; ns++) {
        int n = nbase + ns * 16 + l15;
        int kind = n >> 9;
        int idx = n & 511;
        const float* bpb = kind == 0 ? bq : (kind == 1 ? bk : bv);
        biasv[ns] = bpb[idx];
    }

    #pragma unroll
    for (int ms = 0; ms < 4; ms++) {
        #pragma unroll
        for (int r = 0; r < 4; r++) {
            int m = mbase + ms * 16 + quad * 4 + r;
            int b = m / (TT * HWP);
            int rem = m - b * (TT * HWP);
            int t = rem / HWP;
            int p = rem - t * HWP;
            #pragma unroll
            for (int ns = 0; ns < 4; ns++) {
                int n = nbase + ns * 16 + l15;
                int kind = n >> 9;          // uniform across block (kind = nb>>1)
                int idx = n & 511;
                int head = idx >> 6;
                int ci = idx & 63;
                float val = acc[ms][ns][r] + biasv[ns];
                if (kind == 0) {
                    Qout[(((size_t)(b * NH + head) * TT + t) * HWP + p) * CID + ci]
                        = f2bf(val * LOG2E);
                } else if (kind == 1) {
                    Kout[(((size_t)(b * NH + head) * TP + (t + PPAD)) * HWP + p) * CID + ci]
                        = f2bf(val);
                } else {
                    // 32 real frames only (fits d_out exactly)
                    Vplain[(((size_t)(b * NH + head) * TT + t) * HWP + p) * CID + ci]
                        = f2bf(val);
                }
            }
        }
    }
}

// ---------------------------------------------------------------------------
// Prep 4: Vplain [t][p][ci] (32 real frames) -> Vtp [tp][ci][slot(p)].
// Reads coalesced u32; writes coalesced u32 (slot pairs map to p pairs).
// ---------------------------------------------------------------------------
__global__ __launch_bounds__(256) void v_reformat(
    const u16* __restrict__ Vplain, u16* __restrict__ Vtp)
{
    __shared__ u16 T[HWP * 66];
    int bx = blockIdx.x;
    int t = bx & 31;
    int slab = bx >> 5;
    int tid = threadIdx.x;
    const u32* src = (const u32*)(Vplain + ((size_t)slab * TT + t) * (HWP * CID));
    for (int i = tid; i < HWP * 32; i += 256) {
        int p = i >> 5, c2 = i & 31;
        u32 v = src[i];
        T[p * 66 + c2 * 2]     = (u16)(v & 0xffffu);
        T[p * 66 + c2 * 2 + 1] = (u16)(v >> 16);
    }
    __syncthreads();
    u32* dst = (u32*)(Vtp + ((size_t)slab * TP + (t + PPAD)) * (64 * VSLOT));
    for (int i = tid; i < 64 * 98; i += 256) {
        int ci = i / 98;
        int s2 = i - ci * 98;
        int s = s2 * 2;
        int s5 = s & 31;
        int p0 = (s & ~31) | (((s5 >> 2) & 1) << 4) | ((s5 >> 3) << 2) | (s5 & 3);
        u32 lo = T[p0 * 66 + ci];
        u32 hi = T[(p0 + 1) * 66 + ci];
        dst[ci * (VSLOT / 2) + s2] = lo | (hi << 16);
    }
}

// ---------------------------------------------------------------------------
// MFMA flash attention v3. One block = one wave = (slab, t, 32-q block).
// 7 q-blocks per (slab,t) (224 q-slots vs 196 valid). Per frame: 6 full
// 32-key chunks + 4-key tail. P = exp2(S') packed straight into PV A-frags;
// V from pre-permuted Vtp (contiguous dwordx4); l via mfma(P, ones).
// No loop barriers; XCD swizzle pins each slab to one L2.
// ---------------------------------------------------------------------------
__global__ __launch_bounds__(64, 4) void attn_mfma3(
    const float* __restrict__ x,
    const u16* __restrict__ Qb, const u16* __restrict__ Kb,
    const u16* __restrict__ Vtp, float* __restrict__ zout)
{
    __shared__ float eT[32 * 66];

    int i = blockIdx.x;
    int xcd = i & 7;
    int r = i >> 3;                       // 0..447
    int hi = (r >= 224) ? 1 : 0;
    int inner = r - hi * 224;
    int slab = (hi << 3) | xcd;
    int t = inner / 7;
    int qb = inner - t * 7;
    int b = slab >> 3, n = slab & 7;
    int q0 = qb * 32;

    int lane = threadIdx.x;
    int quad = lane >> 4, l15 = lane & 15;

    const size_t krow0 = (size_t)slab * (TP * HWP);
    const u16* vslab = Vtp + (size_t)slab * (TP * 64 * VSLOT);
    const float tmask = (quad == 0) ? 1.0f : 0.0f;

    // Persistent Q B-frags (pre-scaled by log2e)
    short8 qf[2][2];
    #pragma unroll
    for (int tt = 0; tt < 2; tt++) {
        int qrow = q0 + tt * 16 + l15;
        qrow = qrow < HWP ? qrow : (HWP - 1);
        const u16* qp = Qb + ((size_t)(slab * TT + t) * HWP + qrow) * CID;
        qf[tt][0] = *(const short8*)(qp + quad * 8);
        qf[tt][1] = *(const short8*)(qp + 32 + quad * 8);
    }

    floatx4 acc[2][4];
    floatx4 accl[2];
    #pragma unroll
    for (int tt = 0; tt < 2; tt++) {
        #pragma unroll
        for (int cg = 0; cg < 4; cg++) acc[tt][cg] = (floatx4){0.f, 0.f, 0.f, 0.f};
        accl[tt] = (floatx4){0.f, 0.f, 0.f, 0.f};
    }

    union { u32 w[4]; short8 s; } ones;
    ones.w[0] = 0x3F803F80u; ones.w[1] = 0x3F803F80u;
    ones.w[2] = 0x3F803F80u; ones.w[3] = 0x3F803F80u;

    for (int f = 0; f < KWIN; f++) {
        int rbase = (t + f) * HWP;
        const u16* kframe = Kb + (krow0 + rbase) * CID;
        const u16* vframe = vslab + (size_t)(t + f) * (64 * VSLOT) + l15 * VSLOT;

        for (int c = 0; c < 6; c++) {
            const u16* kp0 = kframe + (size_t)(c * 32 + l15) * CID + quad * 8;
            short8 kf00 = *(const short8*)(kp0);
            short8 kf01 = *(const short8*)(kp0 + 32);
            const u16* kp1 = kp0 + 16 * CID;
            short8 kf10 = *(const short8*)(kp1);
            short8 kf11 = *(const short8*)(kp1 + 32);
            const u16* vp = vframe + c * 32 + quad * 8;
            short8 vf0 = *(const short8*)(vp);
            short8 vf1 = *(const short8*)(vp + 16 * VSLOT);
            short8 vf2 = *(const short8*)(vp + 32 * VSLOT);
            short8 vf3 = *(const short8*)(vp + 48 * VSLOT);

            #pragma unroll
            for (int tt = 0; tt < 2; tt++) {
                floatx4 sc0 = (floatx4){0.f, 0.f, 0.f, 0.f};
                sc0 = __builtin_amdgcn_mfma_f32_16x16x32_bf16(kf00, qf[tt][0], sc0, 0, 0, 0);
                sc0 = __builtin_amdgcn_mfma_f32_16x16x32_bf16(kf01, qf[tt][1], sc0, 0, 0, 0);
                floatx4 sc1 = (floatx4){0.f, 0.f, 0.f, 0.f};
                sc1 = __builtin_amdgcn_mfma_f32_16x16x32_bf16(kf10, qf[tt][0], sc1, 0, 0, 0);
                sc1 = __builtin_amdgcn_mfma_f32_16x16x32_bf16(kf11, qf[tt][1], sc1, 0, 0, 0);

                union { u32 w[4]; short8 s; } pf;
                pf.w[0] = packtrunc(exp2f(sc0[0]), exp2f(sc0[1]));
                pf.w[1] = packtrunc(exp2f(sc0[2]), exp2f(sc0[3]));
                pf.w[2] = packtrunc(exp2f(sc1[0]), exp2f(sc1[1]));
                pf.w[3] = packtrunc(exp2f(sc1[2]), exp2f(sc1[3]));

                acc[tt][0] = __builtin_amdgcn_mfma_f32_16x16x32_bf16(pf.s, vf0, acc[tt][0], 0, 0, 0);
                acc[tt][1] = __builtin_amdgcn_mfma_f32_16x16x32_bf16(pf.s, vf1, acc[tt][1], 0, 0, 0);
                acc[tt][2] = __builtin_amdgcn_mfma_f32_16x16x32_bf16(pf.s, vf2, acc[tt][2], 0, 0, 0);
                acc[tt][3] = __builtin_amdgcn_mfma_f32_16x16x32_bf16(pf.s, vf3, acc[tt][3], 0, 0, 0);
                accl[tt]   = __builtin_amdgcn_mfma_f32_16x16x32_bf16(pf.s, ones.s, accl[tt], 0, 0, 0);
            }
        }

        // Tail chunk: keys 192..195 valid (quad 0 rows of group 0).
        {
            int row0 = rbase + 192 + l15;
            row0 = row0 < (TP * HWP) ? row0 : (TP * HWP - 1);
            const u16* kp0 = Kb + (krow0 + row0) * CID + quad * 8;
            short8 kf00 = *(const short8*)(kp0);
            short8 kf01 = *(const short8*)(kp0 + 32);
            const u16* vp = vframe + 192 + quad * 8;
            short8 vf0 = *(const short8*)(vp);
            short8 vf1 = *(const short8*)(vp + 16 * VSLOT);
            short8 vf2 = *(const short8*)(vp + 32 * VSLOT);
            short8 vf3 = *(const short8*)(vp + 48 * VSLOT);

            #pragma unroll
            for (int tt = 0; tt < 2; tt++) {
                floatx4 sc0 = (floatx4){0.f, 0.f, 0.f, 0.f};
                sc0 = __builtin_amdgcn_mfma_f32_16x16x32_bf16(kf00, qf[tt][0], sc0, 0, 0, 0);
                sc0 = __builtin_amdgcn_mfma_f32_16x16x32_bf16(kf01, qf[tt][1], sc0, 0, 0, 0);

                union { u32 w[4]; short8 s; } pf;
                pf.w[0] = packtrunc(exp2f(sc0[0]) * tmask, exp2f(sc0[1]) * tmask);
                pf.w[1] = packtrunc(exp2f(sc0[2]) * tmask, exp2f(sc0[3]) * tmask);
                pf.w[2] = 0u;
                pf.w[3] = 0u;

                acc[tt][0] = __builtin_amdgcn_mfma_f32_16x16x32_bf16(pf.s, vf0, acc[tt][0], 0, 0, 0);
                acc[tt][1] = __builtin_amdgcn_mfma_f32_16x16x32_bf16(pf.s, vf1, acc[tt][1], 0, 0, 0);
                acc[tt][2] = __builtin_amdgcn_mfma_f32_16x16x32_bf16(pf.s, vf2, acc[tt][2], 0, 0, 0);
                acc[tt][3] = __builtin_amdgcn_mfma_f32_16x16x32_bf16(pf.s, vf3, acc[tt][3], 0, 0, 0);
                accl[tt]   = __builtin_amdgcn_mfma_f32_16x16x32_bf16(pf.s, ones.s, accl[tt], 0, 0, 0);
            }
        }
    }

    // Normalize; transpose through LDS for coalesced z-store + residual.
    #pragma unroll
    for (int tt = 0; tt < 2; tt++) {
        float il[4];
        #pragma unroll
        for (int rr = 0; rr < 4; rr++) il[rr] = 1.0f / accl[tt][rr];
        #pragma unroll
        for (int cg = 0; cg < 4; cg++)
            #pragma unroll
            for (int rr = 0; rr < 4; rr++)
                eT[(tt * 16 + quad * 4 + rr) * 66 + cg * 16 + l15] = acc[tt][cg][rr] * il[rr];
    }
    __syncthreads();

    int pl = lane & 31;
    int half = lane >> 5;
    int p = q0 + pl;
    if (p < HWP) {
        size_t base = ((size_t)(b * CC + n * CID) * TT + t) * HWP + p;
        for (int cc = 0; cc < 32; cc++) {
            int ci = cc + 32 * half;
            size_t a = base + (size_t)ci * (TT * HWP);
            zout[a] = eT[pl * 66 + ci] + x[a];
        }
    }
}

// ---------------------------------------------------------------------------
extern "C" void kernel_launch(void* const* d_in, const int* in_sizes, int n_in,
                              void* d_out, int out_size, void* d_ws, size_t ws_size,
                              hipStream_t stream) {
    const float* x  = (const float*)d_in[0];
    const float* Wq = (const float*)d_in[1];
    const float* bq = (const float*)d_in[2];
    const float* Wk = (const float*)d_in[3];
    const float* bk = (const float*)d_in[4];
    const float* Wv = (const float*)d_in[5];
    const float* bv = (const float*)d_in[6];
    float* z = (float*)d_out;

    // ws (bf16): Q [16][T][HW][CI], K [16][Tp][HW][CI], Vtp [16][Tp][CI][224],
    //            W [1536][512]   (~48.8 MB, proven in rounds 4-5)
    // d_out scratch (dead until z written): xt (12.845 MB) + Vplain 32 real
    // frames (12.845 MB) = exactly out_size*4 bytes.
    const size_t qElems   = (size_t)BB * NH * TT * HWP * CID;   // 6,422,528
    const size_t kElems   = (size_t)BB * NH * TP * HWP * CID;   // 8,028,160
    const size_t vtpElems = (size_t)BB * NH * TP * 64 * VSLOT;  // 9,175,040

    u16* Qw  = (u16*)d_ws;
    u16* Kw  = Qw + qElems;
    u16* Vtp = Kw + kElems;
    u16* Wb  = Vtp + vtpElems;
    u16* Xt  = (u16*)d_out;
    u16* Vpl = Xt + qElems;       // 32-frame Vplain; ends exactly at d_out end

    convert_w<<<(NTOT * CC / 2 + 255) / 256, 256, 0, stream>>>(Wq, Wk, Wv, Wb);
    transpose_x<<<BB * TT * 8, 256, 0, stream>>>(x, Xt);
    {
        const int kper = 2 * NH * 8 * HWP * 32;
        const int vper = 2 * NH * 8 * 64 * (VSLOT / 2);
        pad_fill<<<(kper + vper + 255) / 256, 256, 0, stream>>>(bk, bv, Kw, Vtp);
    }
    proj_gemm<<<(MTOT / 64) * 6, 256, 0, stream>>>(Xt, Wb, bq, bk, bv, Qw, Kw, Vpl);
    v_reformat<<<BB * NH * TT, 256, 0, stream>>>(Vpl, Vtp);
    // 16 slabs * 32 t * 7 q-blocks, XCD-swizzled, one wave per block
    attn_mfma3<<<3584, 64, 0, stream>>>(x, Qw, Kw, Vtp, z);
}

// Round 9
// 292.790 us; speedup vs baseline: 1.2733x; 1.2733x over previous
//
#include <hip/hip_runtime.h>
#include <hip/hip_bf16.h>
#include <stdint.h>
#include <cstddef>

// Problem constants
#define BB  2
#define CC  512
#define TT  32
#define HWP 196   // H*W = 14*14
#define NH  8
#define KWIN 9
#define CID 64    // C / N
#define PPAD 4    // (K-1)/2
#define TP  40    // T + 2P
#define MTOT 12544  // BB*TT*HWP
#define NTOT 1536   // 3*CC (Q|K|V output channels)
#define VSLOT 224   // padded per-frame key slots (7*32)
#define KPITCH 72   // LDS K row pitch (u16): 144 B, 16B-aligned, conflict-free
#define VPITCH 232  // LDS V row pitch (u16): 464 B, 16B-aligned, conflict-free
#define LOG2E 1.44269504f

typedef unsigned short u16;
typedef unsigned int   u32;
typedef __attribute__((ext_vector_type(8))) short short8;
typedef __attribute__((ext_vector_type(4))) float floatx4;

__device__ __forceinline__ u16 f2bf(float f) {
    u32 u = __float_as_uint(f);
    u32 r = (u + 0x7fffu + ((u >> 16) & 1u)) >> 16;
    return (u16)r;
}
__device__ __forceinline__ u32 pack2bf(float a, float b) {
    return (u32)f2bf(a) | ((u32)f2bf(b) << 16);
}
// Truncating pack: [hi16(b) : hi16(a)] in one v_perm_b32.
__device__ __forceinline__ u32 packtrunc(float a, float b) {
    return __builtin_amdgcn_perm(__float_as_uint(b), __float_as_uint(a), 0x07060302u);
}

// ---------------------------------------------------------------------------
// Prep 1: W concat + fp32->bf16.  Wbf[oc][c], oc = kind*512 + n*64 + ci.
// ---------------------------------------------------------------------------
__global__ __launch_bounds__(256) void convert_w(
    const float* __restrict__ Wq, const float* __restrict__ Wk,
    const float* __restrict__ Wv, u16* __restrict__ Wbf)
{
    int id = blockIdx.x * 256 + threadIdx.x;      // one u32 (2 elems) each
    if (id >= NTOT * CC / 2) return;
    int c2 = id & 255;
    int oc = id >> 8;
    int kind = oc >> 9;
    int idx = oc & 511;
    const float* src = (kind == 0 ? Wq : (kind == 1 ? Wk : Wv)) + (size_t)idx * CC + c2 * 2;
    ((u32*)Wbf)[id] = pack2bf(src[0], src[1]);
}

// ---------------------------------------------------------------------------
// Prep 2: transpose x[b][c][t][p] fp32 -> xt[(b*T+t)*HW+p][c] bf16.
// xt lives in d_out (dead until attn overwrites with z).
// ---------------------------------------------------------------------------
__global__ __launch_bounds__(256) void transpose_x(
    const float* __restrict__ x, u16* __restrict__ xt)
{
    __shared__ float T[64 * 197];
    int bx = blockIdx.x;
    int ct = bx & 7; bx >>= 3;
    int t = bx & 31;
    int b = bx >> 5;
    int tid = threadIdx.x;
    const float* src = x + ((size_t)(b * CC + ct * 64) * TT + t) * HWP;
    for (int i = tid; i < 64 * HWP; i += 256) {
        int c = i / HWP;
        int p = i - c * HWP;
        T[c * 197 + p] = src[(size_t)c * (TT * HWP) + p];
    }
    __syncthreads();
    u16* dst = xt + (size_t)((b * TT + t) * HWP) * CC + ct * 64;
    for (int i = tid; i < HWP * 64; i += 256) {
        int p = i >> 6;
        int c = i & 63;
        dst[(size_t)p * CC + c] = f2bf(T[c * 197 + p]);
    }
}

// ---------------------------------------------------------------------------
// Prep 3: fill pad frames (tp in {0..3, 36..39}): K rows and Vtp rows = bias.
// ---------------------------------------------------------------------------
__global__ __launch_bounds__(256) void pad_fill(
    const float* __restrict__ bk, const float* __restrict__ bv,
    u16* __restrict__ Kout, u16* __restrict__ Vtp)
{
    int id = blockIdx.x * 256 + threadIdx.x;
    const int kper = 2 * NH * 8 * HWP * 32;        // 802816 u32 (K)
    const int vper = 2 * NH * 8 * 64 * (VSLOT/2);  // 917504 u32 (Vtp)
    if (id >= kper + vper) return;
    if (id < kper) {
        int i = id;
        int ci2 = i & 31; i >>= 5;
        int p = i % HWP;  i /= HWP;
        int fr = i & 7;   i >>= 3;
        int head = i & 7;
        int b = i >> 3;
        int tp = fr < 4 ? fr : fr + 32;
        const float* bias = bk + head * CID + ci2 * 2;
        size_t addr = (((size_t)(b * NH + head) * TP + tp) * HWP + p) * 32 + ci2;
        ((u32*)Kout)[addr] = pack2bf(bias[0], bias[1]);
    } else {
        int i = id - kper;
        int s2 = i % (VSLOT/2); i /= (VSLOT/2);
        int ci = i & 63; i >>= 6;
        int fr = i & 7;  i >>= 3;
        int head = i & 7;
        int b = i >> 3;
        int tp = fr < 4 ? fr : fr + 32;
        float bias = bv[head * CID + ci];
        size_t addr = (((size_t)(b * NH + head) * TP + tp) * 64 + ci) * (VSLOT/2) + s2;
        ((u32*)Vtp)[addr] = pack2bf(bias, bias);   // whole row = bias[ci]
    }
}

// ---------------------------------------------------------------------------
// MFMA projection GEMM: Out^T[m=(b,t,p), n=oc] = xt[m,c] . Wbf[n,c] + bias[n].
// Q scaled by log2(e). K stored [tp][p][ci]; V stored [t][p][ci] over the 32
// REAL frames only; slot permutation deferred to v_reformat.
// ---------------------------------------------------------------------------
__global__ __launch_bounds__(256) void proj_gemm(
    const u16* __restrict__ xt, const u16* __restrict__ Wbf,
    const float* __restrict__ bq, const float* __restrict__ bk,
    const float* __restrict__ bv,
    u16* __restrict__ Qout, u16* __restrict__ Kout, u16* __restrict__ Vplain)
{
    int bx = blockIdx.x;
    int nb = bx % 6;
    int mt = bx / 6;
    int tid = threadIdx.x;
    int wave = tid >> 6, lane = tid & 63, quad = lane >> 4, l15 = lane & 15;
    int mbase = mt * 64;
    int nbase = nb * 256 + wave * 64;

    floatx4 acc[4][4];
    #pragma unroll
    for (int ms = 0; ms < 4; ms++)
        #pragma unroll
        for (int ns = 0; ns < 4; ns++)
            acc[ms][ns] = (floatx4){0.f, 0.f, 0.f, 0.f};

    const u16* ap[4];
    const u16* bp[4];
    #pragma unroll
    for (int ms = 0; ms < 4; ms++)
        ap[ms] = xt + (size_t)(mbase + ms * 16 + l15) * CC + quad * 8;
    #pragma unroll
    for (int ns = 0; ns < 4; ns++)
        bp[ns] = Wbf + (size_t)(nbase + ns * 16 + l15) * CC + quad * 8;

    #pragma unroll 2
    for (int kc = 0; kc < 16; kc++) {
        short8 af[4], bf[4];
        #pragma unroll
        for (int ms = 0; ms < 4; ms++) af[ms] = *(const short8*)(ap[ms] + kc * 32);
        #pragma unroll
        for (int ns = 0; ns < 4; ns++) bf[ns] = *(const short8*)(bp[ns] + kc * 32);
        #pragma unroll
        for (int ms = 0; ms < 4; ms++)
            #pragma unroll
            for (int ns = 0; ns < 4; ns++)
                acc[ms][ns] = __builtin_amdgcn_mfma_f32_16x16x32_bf16(
                    af[ms], bf[ns], acc[ms][ns], 0, 0, 0);
    }

    float biasv[4];
    #pragma unroll
    for (int ns = 0; ns < 4; ns++) {
        int n = nbase + ns * 16 + l15;
        int kind = n >> 9;
        int idx = n & 511;
        const float* bpb = kind == 0 ? bq : (kind == 1 ? bk : bv);
        biasv[ns] = bpb[idx];
    }

    #pragma unroll
    for (int ms = 0; ms < 4; ms++) {
        #pragma unroll
        for (int r = 0; r < 4; r++) {
            int m = mbase + ms * 16 + quad * 4 + r;
            int b = m / (TT * HWP);
            int rem = m - b * (TT * HWP);
            int t = rem / HWP;
            int p = rem - t * HWP;
            #pragma unroll
            for (int ns = 0; ns < 4; ns++) {
                int n = nbase + ns * 16 + l15;
                int kind = n >> 9;          // uniform across block (kind = nb>>1)
                int idx = n & 511;
                int head = idx >> 6;
                int ci = idx & 63;
                float val = acc[ms][ns][r] + biasv[ns];
                if (kind == 0) {
                    Qout[(((size_t)(b * NH + head) * TT + t) * HWP + p) * CID + ci]
                        = f2bf(val * LOG2E);
                } else if (kind == 1) {
                    Kout[(((size_t)(b * NH + head) * TP + (t + PPAD)) * HWP + p) * CID + ci]
                        = f2bf(val);
                } else {
                    Vplain[(((size_t)(b * NH + head) * TT + t) * HWP + p) * CID + ci]
                        = f2bf(val);
                }
            }
        }
    }
}

// ---------------------------------------------------------------------------
// Prep 4: Vplain [t][p][ci] (32 real frames) -> Vtp [tp][ci][slot(p)].
// ---------------------------------------------------------------------------
__global__ __launch_bounds__(256) void v_reformat(
    const u16* __restrict__ Vplain, u16* __restrict__ Vtp)
{
    __shared__ u16 T[HWP * 66];
    int bx = blockIdx.x;
    int t = bx & 31;
    int slab = bx >> 5;
    int tid = threadIdx.x;
    const u32* src = (const u32*)(Vplain + ((size_t)slab * TT + t) * (HWP * CID));
    for (int i = tid; i < HWP * 32; i += 256) {
        int p = i >> 5, c2 = i & 31;
        u32 v = src[i];
        T[p * 66 + c2 * 2]     = (u16)(v & 0xffffu);
        T[p * 66 + c2 * 2 + 1] = (u16)(v >> 16);
    }
    __syncthreads();
    u32* dst = (u32*)(Vtp + ((size_t)slab * TP + (t + PPAD)) * (64 * VSLOT));
    for (int i = tid; i < 64 * 98; i += 256) {
        int ci = i / 98;
        int s2 = i - ci * 98;
        int s = s2 * 2;
        int s5 = s & 31;
        int p0 = (s & ~31) | (((s5 >> 2) & 1) << 4) | ((s5 >> 3) << 2) | (s5 & 3);
        u32 lo = T[p0 * 66 + ci];
        u32 hi = T[(p0 + 1) * 66 + ci];
        dst[ci * (VSLOT / 2) + s2] = lo | (hi << 16);
    }
}

// ---------------------------------------------------------------------------
// MFMA flash attention v4 (staging fixed). One block = (slab, t), 4 waves,
// 16 q-tiles of 16 (196 valid q). Per frame: block stages K (224 rows, 8
// uint4/row) and V (64 rows, 28 uint4/row) into padded LDS ONCE; all waves
// compute from LDS. Tail chunk (keys 192..195) quad-0-masked. l via
// mfma(P, ones). Epilogue: eT (aliased over sK/sV) -> full-row stores.
// ---------------------------------------------------------------------------
__global__ __launch_bounds__(256, 2) void attn_mfma4(
    const float* __restrict__ x,
    const u16* __restrict__ Qb, const u16* __restrict__ Kb,
    const u16* __restrict__ Vtp, float* __restrict__ zout)
{
    __shared__ union {
        struct { u16 K[224 * KPITCH]; u16 V[64 * VPITCH]; } s;   // 61,952 B
        float eT[HWP * 66];                                      // 51,744 B
    } u;

    int i = blockIdx.x;
    int xcd = i & 7;
    int r = i >> 3;                        // 0..63
    int slab = ((r >= 32) ? 8 : 0) | xcd;  // slab pinned to one XCD
    int t = r & 31;
    int b = slab >> 3, n = slab & 7;

    int tid = threadIdx.x;
    int wave = tid >> 6;
    int lane = tid & 63;
    int quad = lane >> 4, l15 = lane & 15;

    const size_t krow0 = (size_t)slab * (TP * HWP);
    const u16* vslab = Vtp + (size_t)slab * (TP * 64 * VSLOT);
    const float tmask = (quad == 0) ? 1.0f : 0.0f;

    // Persistent Q B-frags: wave w, tiles tg = w + 4*j
    short8 qf[4][2];
    #pragma unroll
    for (int j = 0; j < 4; j++) {
        int qrow = (wave + 4 * j) * 16 + l15;
        qrow = qrow < HWP ? qrow : (HWP - 1);
        const u16* qp = Qb + ((size_t)(slab * TT + t) * HWP + qrow) * CID;
        qf[j][0] = *(const short8*)(qp + quad * 8);
        qf[j][1] = *(const short8*)(qp + 32 + quad * 8);
    }

    floatx4 acc[4][4];
    floatx4 accl[4];
    #pragma unroll
    for (int j = 0; j < 4; j++) {
        #pragma unroll
        for (int cg = 0; cg < 4; cg++) acc[j][cg] = (floatx4){0.f, 0.f, 0.f, 0.f};
        accl[j] = (floatx4){0.f, 0.f, 0.f, 0.f};
    }

    union { u32 w[4]; short8 s; } ones;
    ones.w[0] = 0x3F803F80u; ones.w[1] = 0x3F803F80u;
    ones.w[2] = 0x3F803F80u; ones.w[3] = 0x3F803F80u;

    for (int f = 0; f < KWIN; f++) {
        int rbase = (t + f) * HWP;

        __syncthreads();   // previous frame's LDS reads complete
        // Stage K: 224 rows x 8 uint4-chunks = 1792 chunks, 7/thread.
        {
            const u16* kfr0 = Kb + krow0 * CID;
            #pragma unroll
            for (int it = 0; it < 7; it++) {
                int idx = it * 256 + tid;
                int p = idx >> 3, jj = idx & 7;
                int grow = rbase + p;
                grow = grow < (TP * HWP) ? grow : (TP * HWP - 1);
                uint4 v = *(const uint4*)(kfr0 + (size_t)grow * CID + jj * 8);
                *(uint4*)&u.s.K[p * KPITCH + jj * 8] = v;
            }
        }
        // Stage V: 64 rows x 28 uint4-chunks (448 B/row) = 1792 chunks, 7/thread.
        {
            const u16* vfr = vslab + (size_t)(t + f) * (64 * VSLOT);
            #pragma unroll
            for (int it = 0; it < 7; it++) {
                int idx = it * 256 + tid;
                int ci = idx / 28, jj = idx - ci * 28;
                uint4 v = *(const uint4*)(vfr + ci * VSLOT + jj * 8);
                *(uint4*)&u.s.V[ci * VPITCH + jj * 8] = v;
            }
        }
        __syncthreads();

        // 6 full 32-key chunks
        for (int c = 0; c < 6; c++) {
            const u16* kp0 = &u.s.K[(c * 32 + l15) * KPITCH + quad * 8];
            short8 kf00 = *(const short8*)(kp0);
            short8 kf01 = *(const short8*)(kp0 + 32);
            const u16* kp1 = kp0 + 16 * KPITCH;
            short8 kf10 = *(const short8*)(kp1);
            short8 kf11 = *(const short8*)(kp1 + 32);
            const u16* vp = &u.s.V[l15 * VPITCH + c * 32 + quad * 8];
            short8 vf0 = *(const short8*)(vp);
            short8 vf1 = *(const short8*)(vp + 16 * VPITCH);
            short8 vf2 = *(const short8*)(vp + 32 * VPITCH);
            short8 vf3 = *(const short8*)(vp + 48 * VPITCH);

            #pragma unroll
            for (int j = 0; j < 4; j++) {
                floatx4 sc0 = (floatx4){0.f, 0.f, 0.f, 0.f};
                sc0 = __builtin_amdgcn_mfma_f32_16x16x32_bf16(kf00, qf[j][0], sc0, 0, 0, 0);
                sc0 = __builtin_amdgcn_mfma_f32_16x16x32_bf16(kf01, qf[j][1], sc0, 0, 0, 0);
                floatx4 sc1 = (floatx4){0.f, 0.f, 0.f, 0.f};
                sc1 = __builtin_amdgcn_mfma_f32_16x16x32_bf16(kf10, qf[j][0], sc1, 0, 0, 0);
                sc1 = __builtin_amdgcn_mfma_f32_16x16x32_bf16(kf11, qf[j][1], sc1, 0, 0, 0);

                union { u32 w[4]; short8 s; } pf;
                pf.w[0] = packtrunc(exp2f(sc0[0]), exp2f(sc0[1]));
                pf.w[1] = packtrunc(exp2f(sc0[2]), exp2f(sc0[3]));
                pf.w[2] = packtrunc(exp2f(sc1[0]), exp2f(sc1[1]));
                pf.w[3] = packtrunc(exp2f(sc1[2]), exp2f(sc1[3]));

                acc[j][0] = __builtin_amdgcn_mfma_f32_16x16x32_bf16(pf.s, vf0, acc[j][0], 0, 0, 0);
                acc[j][1] = __builtin_amdgcn_mfma_f32_16x16x32_bf16(pf.s, vf1, acc[j][1], 0, 0, 0);
                acc[j][2] = __builtin_amdgcn_mfma_f32_16x16x32_bf16(pf.s, vf2, acc[j][2], 0, 0, 0);
                acc[j][3] = __builtin_amdgcn_mfma_f32_16x16x32_bf16(pf.s, vf3, acc[j][3], 0, 0, 0);
                accl[j]   = __builtin_amdgcn_mfma_f32_16x16x32_bf16(pf.s, ones.s, accl[j], 0, 0, 0);
            }
        }

        // Tail chunk: keys 192..195 valid (quad-0 rows of group 0).
        {
            const u16* kp0 = &u.s.K[(192 + l15) * KPITCH + quad * 8];
            short8 kf00 = *(const short8*)(kp0);
            short8 kf01 = *(const short8*)(kp0 + 32);
            const u16* vp = &u.s.V[l15 * VPITCH + 192 + quad * 8];
            short8 vf0 = *(const short8*)(vp);
            short8 vf1 = *(const short8*)(vp + 16 * VPITCH);
            short8 vf2 = *(const short8*)(vp + 32 * VPITCH);
            short8 vf3 = *(const short8*)(vp + 48 * VPITCH);

            #pragma unroll
            for (int j = 0; j < 4; j++) {
                floatx4 sc0 = (floatx4){0.f, 0.f, 0.f, 0.f};
                sc0 = __builtin_amdgcn_mfma_f32_16x16x32_bf16(kf00, qf[j][0], sc0, 0, 0, 0);
                sc0 = __builtin_amdgcn_mfma_f32_16x16x32_bf16(kf01, qf[j][1], sc0, 0, 0, 0);

                union { u32 w[4]; short8 s; } pf;
                pf.w[0] = packtrunc(exp2f(sc0[0]) * tmask, exp2f(sc0[1]) * tmask);
                pf.w[1] = packtrunc(exp2f(sc0[2]) * tmask, exp2f(sc0[3]) * tmask);
                pf.w[2] = 0u;
                pf.w[3] = 0u;

                acc[j][0] = __builtin_amdgcn_mfma_f32_16x16x32_bf16(pf.s, vf0, acc[j][0], 0, 0, 0);
                acc[j][1] = __builtin_amdgcn_mfma_f32_16x16x32_bf16(pf.s, vf1, acc[j][1], 0, 0, 0);
                acc[j][2] = __builtin_amdgcn_mfma_f32_16x16x32_bf16(pf.s, vf2, acc[j][2], 0, 0, 0);
                acc[j][3] = __builtin_amdgcn_mfma_f32_16x16x32_bf16(pf.s, vf3, acc[j][3], 0, 0, 0);
                accl[j]   = __builtin_amdgcn_mfma_f32_16x16x32_bf16(pf.s, ones.s, accl[j], 0, 0, 0);
            }
        }
    }

    // Epilogue: normalize into eT (aliases sK/sV), then full-row stores.
    __syncthreads();   // all LDS K/V reads done before aliasing
    #pragma unroll
    for (int j = 0; j < 4; j++) {
        int tg = wave + 4 * j;
        float il[4];
        #pragma unroll
        for (int rr = 0; rr < 4; rr++) il[rr] = 1.0f / accl[j][rr];
        #pragma unroll
        for (int cg = 0; cg < 4; cg++) {
            #pragma unroll
            for (int rr = 0; rr < 4; rr++) {
                int p = tg * 16 + quad * 4 + rr;
                if (p < HWP)
                    u.eT[p * 66 + cg * 16 + l15] = acc[j][cg][rr] * il[rr];
            }
        }
    }
    __syncthreads();

    if (tid < HWP) {
        size_t base = ((size_t)(b * CC + n * CID) * TT + t) * HWP + tid;
        for (int ci = 0; ci < 64; ci++) {
            size_t a = base + (size_t)ci * (TT * HWP);
            zout[a] = u.eT[tid * 66 + ci] + x[a];
        }
    }
}

// ---------------------------------------------------------------------------
extern "C" void kernel_launch(void* const* d_in, const int* in_sizes, int n_in,
                              void* d_out, int out_size, void* d_ws, size_t ws_size,
                              hipStream_t stream) {
    const float* x  = (const float*)d_in[0];
    const float* Wq = (const float*)d_in[1];
    const float* bq = (const float*)d_in[2];
    const float* Wk = (const float*)d_in[3];
    const float* bk = (const float*)d_in[4];
    const float* Wv = (const float*)d_in[5];
    const float* bv = (const float*)d_in[6];
    float* z = (float*)d_out;

    // ws (bf16): Q, K, Vtp, W (~48.8 MB, proven). d_out scratch: xt + Vplain
    // (32 real frames) = exactly out_size*4 bytes (proven round 7).
    const size_t qElems   = (size_t)BB * NH * TT * HWP * CID;   // 6,422,528
    const size_t kElems   = (size_t)BB * NH * TP * HWP * CID;   // 8,028,160
    const size_t vtpElems = (size_t)BB * NH * TP * 64 * VSLOT;  // 9,175,040

    u16* Qw  = (u16*)d_ws;
    u16* Kw  = Qw + qElems;
    u16* Vtp = Kw + kElems;
    u16* Wb  = Vtp + vtpElems;
    u16* Xt  = (u16*)d_out;
    u16* Vpl = Xt + qElems;

    convert_w<<<(NTOT * CC / 2 + 255) / 256, 256, 0, stream>>>(Wq, Wk, Wv, Wb);
    transpose_x<<<BB * TT * 8, 256, 0, stream>>>(x, Xt);
    {
        const int kper = 2 * NH * 8 * HWP * 32;
        const int vper = 2 * NH * 8 * 64 * (VSLOT / 2);
        pad_fill<<<(kper + vper + 255) / 256, 256, 0, stream>>>(bk, bv, Kw, Vtp);
    }
    proj_gemm<<<(MTOT / 64) * 6, 256, 0, stream>>>(Xt, Wb, bq, bk, bv, Qw, Kw, Vpl);
    v_reformat<<<BB * NH * TT, 256, 0, stream>>>(Vpl, Vtp);
    // 16 slabs * 32 t, 4 waves/block, XCD-swizzled; 512 blocks = 2/CU
    attn_mfma4<<<512, 256, 0, stream>>>(x, Qw, Kw, Vtp, z);
}

// Round 10
// 262.985 us; speedup vs baseline: 1.4176x; 1.1133x over previous
//
#include <hip/hip_runtime.h>
#include <hip/hip_bf16.h>
#include <stdint.h>
#include <cstddef>

// Problem constants
#define BB  2
#define CC  512
#define TT  32
#define HWP 196   // H*W = 14*14
#define NH  8
#define KWIN 9
#define CID 64    // C / N
#define PPAD 4    // (K-1)/2
#define TP  40    // T + 2P
#define MTOT 12544  // BB*TT*HWP
#define NTOT 1536   // 3*CC (Q|K|V output channels)
#define VSLOT 224   // padded per-frame key slots (7*32)
#define KPITCH 72   // LDS K row pitch (u16)
#define VPITCH 232  // LDS V row pitch (u16)
#define GPITCH 72   // proj_gemm2 LDS row pitch (u16): 144 B, 16B-aligned
#define LOG2E 1.44269504f

typedef unsigned short u16;
typedef unsigned int   u32;
typedef __attribute__((ext_vector_type(8))) short short8;
typedef __attribute__((ext_vector_type(4))) float floatx4;

__device__ __forceinline__ u16 f2bf(float f) {
    u32 u = __float_as_uint(f);
    u32 r = (u + 0x7fffu + ((u >> 16) & 1u)) >> 16;
    return (u16)r;
}
__device__ __forceinline__ u32 pack2bf(float a, float b) {
    return (u32)f2bf(a) | ((u32)f2bf(b) << 16);
}
// Truncating pack: [hi16(b) : hi16(a)] in one v_perm_b32.
__device__ __forceinline__ u32 packtrunc(float a, float b) {
    return __builtin_amdgcn_perm(__float_as_uint(b), __float_as_uint(a), 0x07060302u);
}

// ---------------------------------------------------------------------------
// Prep 1: W concat + fp32->bf16.  Wbf[oc][c], oc = kind*512 + n*64 + ci.
// ---------------------------------------------------------------------------
__global__ __launch_bounds__(256) void convert_w(
    const float* __restrict__ Wq, const float* __restrict__ Wk,
    const float* __restrict__ Wv, u16* __restrict__ Wbf)
{
    int id = blockIdx.x * 256 + threadIdx.x;      // one u32 (2 elems) each
    if (id >= NTOT * CC / 2) return;
    int c2 = id & 255;
    int oc = id >> 8;
    int kind = oc >> 9;
    int idx = oc & 511;
    const float* src = (kind == 0 ? Wq : (kind == 1 ? Wk : Wv)) + (size_t)idx * CC + c2 * 2;
    ((u32*)Wbf)[id] = pack2bf(src[0], src[1]);
}

// ---------------------------------------------------------------------------
// Prep 2: transpose x[b][c][t][p] fp32 -> xt[(b*T+t)*HW+p][c] bf16.
// xt lives in d_out (dead until attn overwrites with z).
// ---------------------------------------------------------------------------
__global__ __launch_bounds__(256) void transpose_x(
    const float* __restrict__ x, u16* __restrict__ xt)
{
    __shared__ float T[64 * 197];
    int bx = blockIdx.x;
    int ct = bx & 7; bx >>= 3;
    int t = bx & 31;
    int b = bx >> 5;
    int tid = threadIdx.x;
    const float* src = x + ((size_t)(b * CC + ct * 64) * TT + t) * HWP;
    for (int i = tid; i < 64 * HWP; i += 256) {
        int c = i / HWP;
        int p = i - c * HWP;
        T[c * 197 + p] = src[(size_t)c * (TT * HWP) + p];
    }
    __syncthreads();
    u16* dst = xt + (size_t)((b * TT + t) * HWP) * CC + ct * 64;
    for (int i = tid; i < HWP * 64; i += 256) {
        int p = i >> 6;
        int c = i & 63;
        dst[(size_t)p * CC + c] = f2bf(T[c * 197 + p]);
    }
}

// ---------------------------------------------------------------------------
// Prep 3: fill pad frames (tp in {0..3, 36..39}): K rows and Vtp rows = bias.
// ---------------------------------------------------------------------------
__global__ __launch_bounds__(256) void pad_fill(
    const float* __restrict__ bk, const float* __restrict__ bv,
    u16* __restrict__ Kout, u16* __restrict__ Vtp)
{
    int id = blockIdx.x * 256 + threadIdx.x;
    const int kper = 2 * NH * 8 * HWP * 32;        // 802816 u32 (K)
    const int vper = 2 * NH * 8 * 64 * (VSLOT/2);  // 917504 u32 (Vtp)
    if (id >= kper + vper) return;
    if (id < kper) {
        int i = id;
        int ci2 = i & 31; i >>= 5;
        int p = i % HWP;  i /= HWP;
        int fr = i & 7;   i >>= 3;
        int head = i & 7;
        int b = i >> 3;
        int tp = fr < 4 ? fr : fr + 32;
        const float* bias = bk + head * CID + ci2 * 2;
        size_t addr = (((size_t)(b * NH + head) * TP + tp) * HWP + p) * 32 + ci2;
        ((u32*)Kout)[addr] = pack2bf(bias[0], bias[1]);
    } else {
        int i = id - kper;
        int s2 = i % (VSLOT/2); i /= (VSLOT/2);
        int ci = i & 63; i >>= 6;
        int fr = i & 7;  i >>= 3;
        int head = i & 7;
        int b = i >> 3;
        int tp = fr < 4 ? fr : fr + 32;
        float bias = bv[head * CID + ci];
        size_t addr = (((size_t)(b * NH + head) * TP + tp) * 64 + ci) * (VSLOT/2) + s2;
        ((u32*)Vtp)[addr] = pack2bf(bias, bias);   // whole row = bias[ci]
    }
}

// ---------------------------------------------------------------------------
// MFMA projection GEMM v2 (LDS-staged): Out^T[m,n] = xt[m,c].Wbf[n,c]+bias.
// Tile 128m x 256n x BK64; 512 thr = 8 waves (2x4), wave = 64x64 (16 frags).
// A/B staged cooperatively (uint4) into padded LDS; frags via ds_read_b128.
// Epilogue identical to the round-5..9-verified scatter (Q*log2e, K [p][ci],
// Vplain 32 real frames).
// ---------------------------------------------------------------------------
__global__ __launch_bounds__(512) void proj_gemm2(
    const u16* __restrict__ xt, const u16* __restrict__ Wbf,
    const float* __restrict__ bq, const float* __restrict__ bk,
    const float* __restrict__ bv,
    u16* __restrict__ Qout, u16* __restrict__ Kout, u16* __restrict__ Vplain)
{
    __shared__ u16 sA[128 * GPITCH];   // 18,432 B
    __shared__ u16 sB[256 * GPITCH];   // 36,864 B

    int bx = blockIdx.x;
    int nb = bx % 6;
    int mt = bx / 6;
    int tid = threadIdx.x;
    int wave = tid >> 6, lane = tid & 63, quad = lane >> 4, l15 = lane & 15;
    int wm = wave >> 2, wn = wave & 3;
    int mbase = mt * 128 + wm * 64;
    int nbase = nb * 256 + wn * 64;

    floatx4 acc[4][4];
    #pragma unroll
    for (int ms = 0; ms < 4; ms++)
        #pragma unroll
        for (int ns = 0; ns < 4; ns++)
            acc[ms][ns] = (floatx4){0.f, 0.f, 0.f, 0.f};

    const u16* agbase = xt + (size_t)(mt * 128) * CC;
    const u16* bgbase = Wbf + (size_t)(nb * 256) * CC;

    for (int kc = 0; kc < 8; kc++) {
        __syncthreads();
        // Stage A: 128 rows x 8 uint4 (64 u16) = 1024 chunks, 2/thread.
        #pragma unroll
        for (int it = 0; it < 2; it++) {
            int idx = it * 512 + tid;
            int row = idx >> 3, jj = idx & 7;
            uint4 v = *(const uint4*)(agbase + (size_t)row * CC + kc * 64 + jj * 8);
            *(uint4*)&sA[row * GPITCH + jj * 8] = v;
        }
        // Stage B: 256 rows x 8 uint4 = 2048 chunks, 4/thread.
        #pragma unroll
        for (int it = 0; it < 4; it++) {
            int idx = it * 512 + tid;
            int row = idx >> 3, jj = idx & 7;
            uint4 v = *(const uint4*)(bgbase + (size_t)row * CC + kc * 64 + jj * 8);
            *(uint4*)&sB[row * GPITCH + jj * 8] = v;
        }
        __syncthreads();

        #pragma unroll
        for (int kk = 0; kk < 2; kk++) {
            short8 af[4], bf[4];
            #pragma unroll
            for (int ms = 0; ms < 4; ms++)
                af[ms] = *(const short8*)&sA[(wm * 64 + ms * 16 + l15) * GPITCH + kk * 32 + quad * 8];
            #pragma unroll
            for (int ns = 0; ns < 4; ns++)
                bf[ns] = *(const short8*)&sB[(wn * 64 + ns * 16 + l15) * GPITCH + kk * 32 + quad * 8];
            #pragma unroll
            for (int ms = 0; ms < 4; ms++)
                #pragma unroll
                for (int ns = 0; ns < 4; ns++)
                    acc[ms][ns] = __builtin_amdgcn_mfma_f32_16x16x32_bf16(
                        af[ms], bf[ns], acc[ms][ns], 0, 0, 0);
        }
    }

    float biasv[4];
    #pragma unroll
    for (int ns = 0; ns < 4; ns++) {
        int n = nbase + ns * 16 + l15;
        int kind = n >> 9;
        int idx = n & 511;
        const float* bpb = kind == 0 ? bq : (kind == 1 ? bk : bv);
        biasv[ns] = bpb[idx];
    }

    #pragma unroll
    for (int ms = 0; ms < 4; ms++) {
        #pragma unroll
        for (int r = 0; r < 4; r++) {
            int m = mbase + ms * 16 + quad * 4 + r;
            int b = m / (TT * HWP);
            int rem = m - b * (TT * HWP);
            int t = rem / HWP;
            int p = rem - t * HWP;
            #pragma unroll
            for (int ns = 0; ns < 4; ns++) {
                int n = nbase + ns * 16 + l15;
                int kind = n >> 9;          // uniform across block (kind = nb>>1)
                int idx = n & 511;
                int head = idx >> 6;
                int ci = idx & 63;
                float val = acc[ms][ns][r] + biasv[ns];
                if (kind == 0) {
                    Qout[(((size_t)(b * NH + head) * TT + t) * HWP + p) * CID + ci]
                        = f2bf(val * LOG2E);
                } else if (kind == 1) {
                    Kout[(((size_t)(b * NH + head) * TP + (t + PPAD)) * HWP + p) * CID + ci]
                        = f2bf(val);
                } else {
                    Vplain[(((size_t)(b * NH + head) * TT + t) * HWP + p) * CID + ci]
                        = f2bf(val);
                }
            }
        }
    }
}

// ---------------------------------------------------------------------------
// Prep 4: Vplain [t][p][ci] (32 real frames) -> Vtp [tp][ci][slot(p)].
// ---------------------------------------------------------------------------
__global__ __launch_bounds__(256) void v_reformat(
    const u16* __restrict__ Vplain, u16* __restrict__ Vtp)
{
    __shared__ u16 T[HWP * 66];
    int bx = blockIdx.x;
    int t = bx & 31;
    int slab = bx >> 5;
    int tid = threadIdx.x;
    const u32* src = (const u32*)(Vplain + ((size_t)slab * TT + t) * (HWP * CID));
    for (int i = tid; i < HWP * 32; i += 256) {
        int p = i >> 5, c2 = i & 31;
        u32 v = src[i];
        T[p * 66 + c2 * 2]     = (u16)(v & 0xffffu);
        T[p * 66 + c2 * 2 + 1] = (u16)(v >> 16);
    }
    __syncthreads();
    u32* dst = (u32*)(Vtp + ((size_t)slab * TP + (t + PPAD)) * (64 * VSLOT));
    for (int i = tid; i < 64 * 98; i += 256) {
        int ci = i / 98;
        int s2 = i - ci * 98;
        int s = s2 * 2;
        int s5 = s & 31;
        int p0 = (s & ~31) | (((s5 >> 2) & 1) << 4) | ((s5 >> 3) << 2) | (s5 & 3);
        u32 lo = T[p0 * 66 + ci];
        u32 hi = T[(p0 + 1) * 66 + ci];
        dst[ci * (VSLOT / 2) + s2] = lo | (hi << 16);
    }
}

// ---------------------------------------------------------------------------
// MFMA flash attention v4 (round-9 verified, unchanged). One block = (slab,t),
// 4 waves, 16 q-tiles; K/V staged once per frame into padded LDS.
// ---------------------------------------------------------------------------
__global__ __launch_bounds__(256, 2) void attn_mfma4(
    const float* __restrict__ x,
    const u16* __restrict__ Qb, const u16* __restrict__ Kb,
    const u16* __restrict__ Vtp, float* __restrict__ zout)
{
    __shared__ union {
        struct { u16 K[224 * KPITCH]; u16 V[64 * VPITCH]; } s;   // 61,952 B
        float eT[HWP * 66];                                      // 51,744 B
    } u;

    int i = blockIdx.x;
    int xcd = i & 7;
    int r = i >> 3;                        // 0..63
    int slab = ((r >= 32) ? 8 : 0) | xcd;  // slab pinned to one XCD
    int t = r & 31;
    int b = slab >> 3, n = slab & 7;

    int tid = threadIdx.x;
    int wave = tid >> 6;
    int lane = tid & 63;
    int quad = lane >> 4, l15 = lane & 15;

    const size_t krow0 = (size_t)slab * (TP * HWP);
    const u16* vslab = Vtp + (size_t)slab * (TP * 64 * VSLOT);
    const float tmask = (quad == 0) ? 1.0f : 0.0f;

    // Persistent Q B-frags: wave w, tiles tg = w + 4*j
    short8 qf[4][2];
    #pragma unroll
    for (int j = 0; j < 4; j++) {
        int qrow = (wave + 4 * j) * 16 + l15;
        qrow = qrow < HWP ? qrow : (HWP - 1);
        const u16* qp = Qb + ((size_t)(slab * TT + t) * HWP + qrow) * CID;
        qf[j][0] = *(const short8*)(qp + quad * 8);
        qf[j][1] = *(const short8*)(qp + 32 + quad * 8);
    }

    floatx4 acc[4][4];
    floatx4 accl[4];
    #pragma unroll
    for (int j = 0; j < 4; j++) {
        #pragma unroll
        for (int cg = 0; cg < 4; cg++) acc[j][cg] = (floatx4){0.f, 0.f, 0.f, 0.f};
        accl[j] = (floatx4){0.f, 0.f, 0.f, 0.f};
    }

    union { u32 w[4]; short8 s; } ones;
    ones.w[0] = 0x3F803F80u; ones.w[1] = 0x3F803F80u;
    ones.w[2] = 0x3F803F80u; ones.w[3] = 0x3F803F80u;

    for (int f = 0; f < KWIN; f++) {
        int rbase = (t + f) * HWP;

        __syncthreads();   // previous frame's LDS reads complete
        // Stage K: 224 rows x 8 uint4-chunks = 1792 chunks, 7/thread.
        {
            const u16* kfr0 = Kb + krow0 * CID;
            #pragma unroll
            for (int it = 0; it < 7; it++) {
                int idx = it * 256 + tid;
                int p = idx >> 3, jj = idx & 7;
                int grow = rbase + p;
                grow = grow < (TP * HWP) ? grow : (TP * HWP - 1);
                uint4 v = *(const uint4*)(kfr0 + (size_t)grow * CID + jj * 8);
                *(uint4*)&u.s.K[p * KPITCH + jj * 8] = v;
            }
        }
        // Stage V: 64 rows x 28 uint4-chunks (448 B/row) = 1792 chunks, 7/thread.
        {
            const u16* vfr = vslab + (size_t)(t + f) * (64 * VSLOT);
            #pragma unroll
            for (int it = 0; it < 7; it++) {
                int idx = it * 256 + tid;
                int ci = idx / 28, jj = idx - ci * 28;
                uint4 v = *(const uint4*)(vfr + ci * VSLOT + jj * 8);
                *(uint4*)&u.s.V[ci * VPITCH + jj * 8] = v;
            }
        }
        __syncthreads();

        // 6 full 32-key chunks
        for (int c = 0; c < 6; c++) {
            const u16* kp0 = &u.s.K[(c * 32 + l15) * KPITCH + quad * 8];
            short8 kf00 = *(const short8*)(kp0);
            short8 kf01 = *(const short8*)(kp0 + 32);
            const u16* kp1 = kp0 + 16 * KPITCH;
            short8 kf10 = *(const short8*)(kp1);
            short8 kf11 = *(const short8*)(kp1 + 32);
            const u16* vp = &u.s.V[l15 * VPITCH + c * 32 + quad * 8];
            short8 vf0 = *(const short8*)(vp);
            short8 vf1 = *(const short8*)(vp + 16 * VPITCH);
            short8 vf2 = *(const short8*)(vp + 32 * VPITCH);
            short8 vf3 = *(const short8*)(vp + 48 * VPITCH);

            #pragma unroll
            for (int j = 0; j < 4; j++) {
                floatx4 sc0 = (floatx4){0.f, 0.f, 0.f, 0.f};
                sc0 = __builtin_amdgcn_mfma_f32_16x16x32_bf16(kf00, qf[j][0], sc0, 0, 0, 0);
                sc0 = __builtin_amdgcn_mfma_f32_16x16x32_bf16(kf01, qf[j][1], sc0, 0, 0, 0);
                floatx4 sc1 = (floatx4){0.f, 0.f, 0.f, 0.f};
                sc1 = __builtin_amdgcn_mfma_f32_16x16x32_bf16(kf10, qf[j][0], sc1, 0, 0, 0);
                sc1 = __builtin_amdgcn_mfma_f32_16x16x32_bf16(kf11, qf[j][1], sc1, 0, 0, 0);

                union { u32 w[4]; short8 s; } pf;
                pf.w[0] = packtrunc(exp2f(sc0[0]), exp2f(sc0[1]));
                pf.w[1] = packtrunc(exp2f(sc0[2]), exp2f(sc0[3]));
                pf.w[2] = packtrunc(exp2f(sc1[0]), exp2f(sc1[1]));
                pf.w[3] = packtrunc(exp2f(sc1[2]), exp2f(sc1[3]));

                acc[j][0] = __builtin_amdgcn_mfma_f32_16x16x32_bf16(pf.s, vf0, acc[j][0], 0, 0, 0);
                acc[j][1] = __builtin_amdgcn_mfma_f32_16x16x32_bf16(pf.s, vf1, acc[j][1], 0, 0, 0);
                acc[j][2] = __builtin_amdgcn_mfma_f32_16x16x32_bf16(pf.s, vf2, acc[j][2], 0, 0, 0);
                acc[j][3] = __builtin_amdgcn_mfma_f32_16x16x32_bf16(pf.s, vf3, acc[j][3], 0, 0, 0);
                accl[j]   = __builtin_amdgcn_mfma_f32_16x16x32_bf16(pf.s, ones.s, accl[j], 0, 0, 0);
            }
        }

        // Tail chunk: keys 192..195 valid (quad-0 rows of group 0).
        {
            const u16* kp0 = &u.s.K[(192 + l15) * KPITCH + quad * 8];
            short8 kf00 = *(const short8*)(kp0);
            short8 kf01 = *(const short8*)(kp0 + 32);
            const u16* vp = &u.s.V[l15 * VPITCH + 192 + quad * 8];
            short8 vf0 = *(const short8*)(vp);
            short8 vf1 = *(const short8*)(vp + 16 * VPITCH);
            short8 vf2 = *(const short8*)(vp + 32 * VPITCH);
            short8 vf3 = *(const short8*)(vp + 48 * VPITCH);

            #pragma unroll
            for (int j = 0; j < 4; j++) {
                floatx4 sc0 = (floatx4){0.f, 0.f, 0.f, 0.f};
                sc0 = __builtin_amdgcn_mfma_f32_16x16x32_bf16(kf00, qf[j][0], sc0, 0, 0, 0);
                sc0 = __builtin_amdgcn_mfma_f32_16x16x32_bf16(kf01, qf[j][1], sc0, 0, 0, 0);

                union { u32 w[4]; short8 s; } pf;
                pf.w[0] = packtrunc(exp2f(sc0[0]) * tmask, exp2f(sc0[1]) * tmask);
                pf.w[1] = packtrunc(exp2f(sc0[2]) * tmask, exp2f(sc0[3]) * tmask);
                pf.w[2] = 0u;
                pf.w[3] = 0u;

                acc[j][0] = __builtin_amdgcn_mfma_f32_16x16x32_bf16(pf.s, vf0, acc[j][0], 0, 0, 0);
                acc[j][1] = __builtin_amdgcn_mfma_f32_16x16x32_bf16(pf.s, vf1, acc[j][1], 0, 0, 0);
                acc[j][2] = __builtin_amdgcn_mfma_f32_16x16x32_bf16(pf.s, vf2, acc[j][2], 0, 0, 0);
                acc[j][3] = __builtin_amdgcn_mfma_f32_16x16x32_bf16(pf.s, vf3, acc[j][3], 0, 0, 0);
                accl[j]   = __builtin_amdgcn_mfma_f32_16x16x32_bf16(pf.s, ones.s, accl[j], 0, 0, 0);
            }
        }
    }

    // Epilogue: normalize into eT (aliases sK/sV), then full-row stores.
    __syncthreads();   // all LDS K/V reads done before aliasing
    #pragma unroll
    for (int j = 0; j < 4; j++) {
        int tg = wave + 4 * j;
        float il[4];
        #pragma unroll
        for (int rr = 0; rr < 4; rr++) il[rr] = 1.0f / accl[j][rr];
        #pragma unroll
        for (int cg = 0; cg < 4; cg++) {
            #pragma unroll
            for (int rr = 0; rr < 4; rr++) {
                int p = tg * 16 + quad * 4 + rr;
                if (p < HWP)
                    u.eT[p * 66 + cg * 16 + l15] = acc[j][cg][rr] * il[rr];
            }
        }
    }
    __syncthreads();

    if (tid < HWP) {
        size_t base = ((size_t)(b * CC + n * CID) * TT + t) * HWP + tid;
        for (int ci = 0; ci < 64; ci++) {
            size_t a = base + (size_t)ci * (TT * HWP);
            zout[a] = u.eT[tid * 66 + ci] + x[a];
        }
    }
}

// ---------------------------------------------------------------------------
extern "C" void kernel_launch(void* const* d_in, const int* in_sizes, int n_in,
                              void* d_out, int out_size, void* d_ws, size_t ws_size,
                              hipStream_t stream) {
    const float* x  = (const float*)d_in[0];
    const float* Wq = (const float*)d_in[1];
    const float* bq = (const float*)d_in[2];
    const float* Wk = (const float*)d_in[3];
    const float* bk = (const float*)d_in[4];
    const float* Wv = (const float*)d_in[5];
    const float* bv = (const float*)d_in[6];
    float* z = (float*)d_out;

    // ws (bf16): Q, K, Vtp, W (~48.8 MB, proven). d_out scratch: xt + Vplain
    // (32 real frames) = exactly out_size*4 bytes (proven rounds 7-9).
    const size_t qElems   = (size_t)BB * NH * TT * HWP * CID;   // 6,422,528
    const size_t kElems   = (size_t)BB * NH * TP * HWP * CID;   // 8,028,160
    const size_t vtpElems = (size_t)BB * NH * TP * 64 * VSLOT;  // 9,175,040

    u16* Qw  = (u16*)d_ws;
    u16* Kw  = Qw + qElems;
    u16* Vtp = Kw + kElems;
    u16* Wb  = Vtp + vtpElems;
    u16* Xt  = (u16*)d_out;
    u16* Vpl = Xt + qElems;

    convert_w<<<(NTOT * CC / 2 + 255) / 256, 256, 0, stream>>>(Wq, Wk, Wv, Wb);
    transpose_x<<<BB * TT * 8, 256, 0, stream>>>(x, Xt);
    {
        const int kper = 2 * NH * 8 * HWP * 32;
        const int vper = 2 * NH * 8 * 64 * (VSLOT / 2);
        pad_fill<<<(kper + vper + 255) / 256, 256, 0, stream>>>(bk, bv, Kw, Vtp);
    }
    // 98 m-tiles (128 rows) x 6 n-tiles (256 cols), 512 threads = 8 waves
    proj_gemm2<<<98 * 6, 512, 0, stream>>>(Xt, Wb, bq, bk, bv, Qw, Kw, Vpl);
    v_reformat<<<BB * NH * TT, 256, 0, stream>>>(Vpl, Vtp);
    // 16 slabs * 32 t, 4 waves/block, XCD-swizzled; 512 blocks = 2/CU
    attn_mfma4<<<512, 256, 0, stream>>>(x, Qw, Kw, Vtp, z);
}